// Round 10
// baseline (413.508 us; speedup 1.0000x reference)
//
#include <hip/hip_runtime.h>
#include <hip/hip_bf16.h>
#include <hip/hip_fp16.h>
#include <cstdint>

#define NODES   150000
#define DIM     64
#define EDGES   4000000
#define LABELS  8192
#define NUSERS  100000
#define NITEMS  50000

#define NB      586          // ceil(NODES/256) coarse buckets of 256 nodes
#define CAP     10240        // LDS entry capacity per bucket (mean 6827, +41 sigma)

typedef float f32x4 __attribute__((ext_vector_type(4)));

// ---- pass A: coarse histogram (LDS-privatized) ----
__global__ void k_chist(const int* __restrict__ col, int* __restrict__ chist) {
    __shared__ int h[NB];
    for (int i = threadIdx.x; i < NB; i += 256) h[i] = 0;
    __syncthreads();
    int base = blockIdx.x * 4096;
    #pragma unroll
    for (int k = 0; k < 16; ++k) {
        int e = base + k * 256 + threadIdx.x;
        if (e < EDGES) atomicAdd(&h[col[e] >> 8], 1);
    }
    __syncthreads();
    for (int i = threadIdx.x; i < NB; i += 256) if (h[i]) atomicAdd(&chist[i], h[i]);
}

// ---- scan of 586 bucket counts (one wave, shuffle scan) ----
__global__ void k_scanB(const int* __restrict__ chist, int* __restrict__ cbase,
                        int* __restrict__ gcur) {
    int lane = threadIdx.x;
    int run = 0;
    for (int base = 0; base < NB; base += 64) {
        int idx = base + lane;
        int v = (idx < NB) ? chist[idx] : 0;
        int inc = v;
        #pragma unroll
        for (int o = 1; o < 64; o <<= 1) {
            int t = __shfl_up(inc, o);
            if (lane >= o) inc += t;
        }
        int ex = run + inc - v;
        if (idx < NB) { cbase[idx] = ex; gcur[idx] = ex; }
        run += __shfl(inc, 63);
    }
    if (lane == 0) cbase[NB] = EDGES;
}

// ---- pass B: coarse scatter into bucket-partitioned packed array ----
__global__ void k_cscatter(const int* __restrict__ row, const int* __restrict__ col,
                           int* __restrict__ gcur, unsigned* __restrict__ E) {
    __shared__ int lhist[NB];
    __shared__ int lbase[NB];
    for (int i = threadIdx.x; i < NB; i += 256) lhist[i] = 0;
    __syncthreads();
    int base = blockIdx.x * 8192;
    #pragma unroll
    for (int k = 0; k < 32; ++k) {
        int e = base + k * 256 + threadIdx.x;
        if (e < EDGES) atomicAdd(&lhist[col[e] >> 8], 1);
    }
    __syncthreads();
    for (int i = threadIdx.x; i < NB; i += 256) {
        int c = lhist[i];
        lbase[i] = c ? atomicAdd(&gcur[i], c) : 0;
        lhist[i] = 0;                       // reuse as local cursor
    }
    __syncthreads();
    #pragma unroll
    for (int k = 0; k < 32; ++k) {
        int e = base + k * 256 + threadIdx.x;
        if (e < EDGES) {
            int c = col[e];
            int b = c >> 8;
            int r = atomicAdd(&lhist[b], 1);
            E[lbase[b] + r] = ((unsigned)(c & 255) << 18) | (unsigned)row[e];
        }
    }
}

// ---- pass C: fine sort within one bucket; also emits rowptr, dis, y0 ----
__global__ void k_fsort(const unsigned* __restrict__ E, const int* __restrict__ cbase,
                        const float* __restrict__ emb, int* __restrict__ src_s,
                        int* __restrict__ rowptr, float* __restrict__ dis,
                        __half2* __restrict__ y0) {
    __shared__ unsigned ebuf[CAP];
    __shared__ int hist[256];
    __shared__ int curs[256];
    __shared__ float sdis[256];
    int b = blockIdx.x;
    int base = cbase[b], end = cbase[b + 1];
    int cnt = end - base;
    int t = threadIdx.x;
    hist[t] = 0;
    __syncthreads();
    for (int i = t; i < cnt; i += 256) {
        unsigned p = E[base + i];
        if (i < CAP) ebuf[i] = p;
        atomicAdd(&hist[p >> 18], 1);
    }
    __syncthreads();
    int v = hist[t];
    int inc = v;
    #pragma unroll
    for (int o = 1; o < 256; o <<= 1) {
        int tmp = (t >= o) ? hist[t - o] : 0;
        __syncthreads();
        hist[t] = inc = inc + tmp;
        __syncthreads();
    }
    int ex = inc - v;
    curs[t] = ex;
    int node = (b << 8) + t;
    float dv = (node < NODES && v > 0) ? rsqrtf((float)v) : 0.0f;
    sdis[t] = dv;
    if (node < NODES) {
        rowptr[node] = base + ex;
        dis[node] = dv;
    }
    if (b == NB - 1 && t == 0) rowptr[NODES] = EDGES;
    __syncthreads();
    for (int i = t; i < cnt; i += 256) {
        unsigned p = (i < CAP) ? ebuf[i] : E[base + i];
        int c = p >> 18;
        int r = atomicAdd(&curs[c], 1);
        src_s[base + r] = (int)(p & 0x3FFFFu);
    }
    // fused k_prep: y0 = f16(dis ⊙ emb) for this bucket's 256 nodes
    int nbase = b << 8;
    for (int i = t; i < 8192; i += 256) {
        int nl = i >> 5, q = i & 31;
        int n2 = nbase + nl;
        if (n2 < NODES) {
            float2 e2 = ((const float2*)emb)[(n2 << 5) + q];
            float d = sdis[nl];
            y0[(n2 << 5) + q] = __floats2half2_rn(e2.x * d, e2.y * d);
        }
    }
}

// Edge-sum core, half-wave paired, f16 packed accumulation.
// Lanes 0-31 even edges, 32-63 odd edges; lane q=l&31 owns dims {2q,2q+1}.
// All __shfl are executed by all 64 lanes (uniform conditions only).
__device__ __forceinline__ __half2 edge_sum2h(const __half2* __restrict__ yd,
                                              const int* __restrict__ src_s,
                                              int jb, int deg, int lane) {
    int h = lane >> 5;
    int q = lane & 31;
    __half2 z = __floats2half2_rn(0.f, 0.f);
    __half2 a0 = z, a1 = z, a2 = z, a3 = z, a4 = z, a5 = z, a6 = z, a7 = z;
    for (int base = 0; base < deg; base += 64) {
        int rem = deg - base;
        int m   = rem < 64 ? rem : 64;
        int idx = (base + lane < deg) ? src_s[jb + base + lane] : 0;
        int j = 0;
        for (; j + 16 <= m; j += 16) {
            int s0 = __shfl(idx, j +  0 + h);
            int s1 = __shfl(idx, j +  2 + h);
            int s2 = __shfl(idx, j +  4 + h);
            int s3 = __shfl(idx, j +  6 + h);
            int s4 = __shfl(idx, j +  8 + h);
            int s5 = __shfl(idx, j + 10 + h);
            int s6 = __shfl(idx, j + 12 + h);
            int s7 = __shfl(idx, j + 14 + h);
            __half2 d0 = yd[(s0 << 5) + q];
            __half2 d1 = yd[(s1 << 5) + q];
            __half2 d2 = yd[(s2 << 5) + q];
            __half2 d3 = yd[(s3 << 5) + q];
            __half2 d4 = yd[(s4 << 5) + q];
            __half2 d5 = yd[(s5 << 5) + q];
            __half2 d6 = yd[(s6 << 5) + q];
            __half2 d7 = yd[(s7 << 5) + q];
            a0 = __hadd2(a0, d0); a1 = __hadd2(a1, d1);
            a2 = __hadd2(a2, d2); a3 = __hadd2(a3, d3);
            a4 = __hadd2(a4, d4); a5 = __hadd2(a5, d5);
            a6 = __hadd2(a6, d6); a7 = __hadd2(a7, d7);
        }
        for (; j + 2 <= m; j += 2) {
            int s = __shfl(idx, j + h);
            a0 = __hadd2(a0, yd[(s << 5) + q]);
        }
        if (j < m) {                          // odd leftover
            int s = __shfl(idx, j);           // uniform shuffle
            if (h == 0) a0 = __hadd2(a0, yd[(s << 5) + q]);
        }
    }
    __half2 r = __hadd2(__hadd2(__hadd2(a0, a1), __hadd2(a2, a3)),
                        __hadd2(__hadd2(a4, a5), __hadd2(a6, a7)));
    return r;
}

__device__ __forceinline__ float2 crosshalf_f32(__half2 a) {
    int ai = *reinterpret_cast<int*>(&a);
    int bi = __shfl_xor(ai, 32);
    __half2 b = *reinterpret_cast<__half2*>(&bi);
    float2 r;
    r.x = __low2float(a)  + __low2float(b);
    r.y = __high2float(a) + __high2float(b);
    return r;
}

// ---- layers 1,2:  yn[n] = f16(dis[n]^2 * sum y[src]) ----
__global__ void k_gather(const __half2* __restrict__ y, const int* __restrict__ src_s,
                         const int* __restrict__ rowptr, const float* __restrict__ dis,
                         __half2* __restrict__ yn) {
    int n    = (blockIdx.x << 2) + (threadIdx.x >> 6);
    int lane = threadIdx.x & 63;
    if (n >= NODES) return;
    int jb  = rowptr[n];
    int deg = rowptr[n + 1] - jb;
    __half2 ah = edge_sum2h(y, src_s, jb, deg, lane);
    float2 a = crosshalf_f32(ah);
    float dd = dis[n]; dd = dd * dd;
    if (lane < 32) {
        yn[(n << 5) + (lane & 31)] = __floats2half2_rn(dd * a.x, dd * a.y);
    }
}

// ---- layer 3 fused with combine + item L2-normalize ----
__global__ void k_gather3(const __half2* __restrict__ y2,
                          const __half2* __restrict__ y1,
                          const float* __restrict__ emb, const int* __restrict__ src_s,
                          const int* __restrict__ rowptr, const float* __restrict__ dis,
                          const float* __restrict__ alpha, const float* __restrict__ sf,
                          float* __restrict__ acc) {
    int n    = (blockIdx.x << 2) + (threadIdx.x >> 6);
    int lane = threadIdx.x & 63;
    if (n >= NODES) return;
    int q  = lane & 31;
    int jb = rowptr[n];
    int deg = rowptr[n + 1] - jb;
    __half2 ah = edge_sum2h(y2, src_s, jb, deg, lane);
    float2 a = crosshalf_f32(ah);
    float d   = dis[n];
    float inv = d > 0.0f ? 1.0f / d : 0.0f;
    int   o32 = (n << 5) + q;
    float2 e2 = ((const float2*)emb)[o32];
    __half2 y1d = y1[o32];
    __half2 y2d = y2[o32];
    float a0 = alpha[0], a1 = alpha[1], a2 = alpha[2], a3 = alpha[3];
    float2 v;
    v.x = a0 * e2.x + inv * (a1 * __low2float(y1d)  + a2 * __low2float(y2d))  + a3 * d * a.x;
    v.y = a0 * e2.y + inv * (a1 * __high2float(y1d) + a2 * __high2float(y2d)) + a3 * d * a.y;
    if (n >= NUSERS) {
        float ss = v.x * v.x + v.y * v.y;
        #pragma unroll
        for (int m = 1; m < 32; m <<= 1) ss += __shfl_xor(ss, m);
        float nrm = fmaxf(sqrtf(ss), 1e-12f);
        float sc  = sf[0] / nrm;
        v.x *= sc; v.y *= sc;
    }
    if (lane < 32) ((float2*)acc)[o32] = v;
}

// ---- rank[k] = dot(acc[src[k]], acc[dst[k]]) : 32 lanes per pair, float2 ----
__global__ void k_rank(const float* __restrict__ acc, const int* __restrict__ eli,
                       float* __restrict__ rank) {
    int k    = (blockIdx.x << 3) + (threadIdx.x >> 5);
    int q    = threadIdx.x & 31;
    if (k >= LABELS) return;
    int s = eli[k];
    int d = eli[LABELS + k];
    float2 vs = ((const float2*)acc)[(s << 5) + q];
    float2 vd = ((const float2*)acc)[(d << 5) + q];
    float p = vs.x * vd.x + vs.y * vd.y;
    #pragma unroll
    for (int m = 1; m < 32; m <<= 1) p += __shfl_xor(p, m);
    if (q == 0) rank[k] = p;
}

// ---- out[which][i][j] = rank[which*4096+j] + beta[eli[LABELS+which*4096+i]] ----
__global__ void k_final(const float* __restrict__ rank, const float* __restrict__ beta,
                        const int* __restrict__ eli, float* __restrict__ out) {
    int t     = blockIdx.x * blockDim.x + threadIdx.x;   // [0, 2^23)
    int which = t >> 22;
    int tt    = t & ((1 << 22) - 1);
    int i     = tt >> 10;
    int j4    = (tt & 1023) << 2;
    int item  = eli[LABELS + (which << 12) + i];
    float b   = beta[item];
    const float* rk = rank + (which << 12);
    float4 r = *reinterpret_cast<const float4*>(rk + j4);
    f32x4 vv = { r.x + b, r.y + b, r.z + b, r.w + b };
    __builtin_nontemporal_store(vv, reinterpret_cast<f32x4*>(out + ((size_t)t << 2)));
}

extern "C" void kernel_launch(void* const* d_in, const int* in_sizes, int n_in,
                              void* d_out, int out_size, void* d_ws, size_t ws_size,
                              hipStream_t stream) {
    const float* emb   = (const float*)d_in[0];
    const float* beta  = (const float*)d_in[1];
    const float* alpha = (const float*)d_in[2];
    const int*   eidx  = (const int*)d_in[3];
    const int*   eli   = (const int*)d_in[4];
    const float* sf    = (const float*)d_in[7];

    const int* row = eidx;
    const int* col = eidx + EDGES;

    // ---- workspace layout (4-byte units) ----
    char* ws = (char*)d_ws;
    int*      rowptr = (int*)     (ws);                   // NODES+1
    float*    dis    = (float*)   (ws + 151552u * 4);     // NODES
    int*      chist  = (int*)     (ws + 303104u * 4);     // NB (pad 1024)
    int*      cbase  = (int*)     (ws + 304128u * 4);     // NB+1 (pad 1024)
    int*      gcur   = (int*)     (ws + 305152u * 4);     // NB (pad 1024)
    float*    rank   = (float*)   (ws + 306176u * 4);     // LABELS
    unsigned* E      = (unsigned*)(ws + 315392u * 4);     // EDGES
    int*      src_s  = (int*)     (ws + 4315392u * 4);    // EDGES

    // acc (f32) in front of d_out; f16 y buffers in its tail
    float* acc = (float*)d_out;                           // 9.6M f32
    __half2* yb = (__half2*)((char*)d_out + 10485760u * 4);
    __half2* Y0 = yb;                                     // 4.8M half2 each, 5M spacing
    __half2* Y1 = yb + 5000000u;
    __half2* Y2 = yb + 10000000u;

    const int NN4 = (NODES + 3) / 4;

    // ---- CSR build (two-level counting sort; emits rowptr + dis + y0) ----
    hipMemsetAsync(chist, 0, 1024 * sizeof(int), stream);
    k_chist<<<(EDGES + 4095) / 4096, 256, 0, stream>>>(col, chist);
    k_scanB<<<1, 64, 0, stream>>>(chist, cbase, gcur);
    k_cscatter<<<(EDGES + 8191) / 8192, 256, 0, stream>>>(row, col, gcur, E);
    k_fsort<<<NB, 256, 0, stream>>>(E, cbase, emb, src_s, rowptr, dis, Y0);

    // ---- propagation (f16 y-space) ----
    k_gather<<<NN4, 256, 0, stream>>>(Y0, src_s, rowptr, dis, Y1);
    k_gather<<<NN4, 256, 0, stream>>>(Y1, src_s, rowptr, dis, Y2);
    k_gather3<<<NN4, 256, 0, stream>>>(Y2, Y1, emb, src_s, rowptr, dis, alpha, sf, acc);

    // ---- epilogue ----
    k_rank<<<LABELS / 8, 256, 0, stream>>>(acc, eli, rank);
    k_final<<<(1 << 23) / 256, 256, 0, stream>>>(rank, beta, eli, (float*)d_out);
}

// Round 11
// 362.498 us; speedup vs baseline: 1.1407x; 1.1407x over previous
//
#include <hip/hip_runtime.h>
#include <hip/hip_bf16.h>
#include <hip/hip_fp16.h>
#include <cstdint>

#define NODES   150000
#define DIM     64
#define EDGES   4000000
#define LABELS  8192
#define NUSERS  100000
#define NITEMS  50000

#define NB      586          // ceil(NODES/256) coarse buckets of 256 nodes
#define CAP     10240        // LDS entry capacity per bucket (mean 6827, +41 sigma)

#define YSCALE  1024.0f      // power-of-two pre-scale so y fits e4m3 normal range
#define IYSCALE (1.0f / 1024.0f)

typedef float f32x4 __attribute__((ext_vector_type(4)));
typedef float f32x2 __attribute__((ext_vector_type(2)));

// ---- pass A: coarse histogram (LDS-privatized) ----
__global__ void k_chist(const int* __restrict__ col, int* __restrict__ chist) {
    __shared__ int h[NB];
    for (int i = threadIdx.x; i < NB; i += 256) h[i] = 0;
    __syncthreads();
    int base = blockIdx.x * 4096;
    #pragma unroll
    for (int k = 0; k < 16; ++k) {
        int e = base + k * 256 + threadIdx.x;
        if (e < EDGES) atomicAdd(&h[col[e] >> 8], 1);
    }
    __syncthreads();
    for (int i = threadIdx.x; i < NB; i += 256) if (h[i]) atomicAdd(&chist[i], h[i]);
}

// ---- scan of 586 bucket counts (one wave, shuffle scan) ----
__global__ void k_scanB(const int* __restrict__ chist, int* __restrict__ cbase,
                        int* __restrict__ gcur) {
    int lane = threadIdx.x;
    int run = 0;
    for (int base = 0; base < NB; base += 64) {
        int idx = base + lane;
        int v = (idx < NB) ? chist[idx] : 0;
        int inc = v;
        #pragma unroll
        for (int o = 1; o < 64; o <<= 1) {
            int t = __shfl_up(inc, o);
            if (lane >= o) inc += t;
        }
        int ex = run + inc - v;
        if (idx < NB) { cbase[idx] = ex; gcur[idx] = ex; }
        run += __shfl(inc, 63);
    }
    if (lane == 0) cbase[NB] = EDGES;
}

// ---- pass B: coarse scatter into bucket-partitioned packed array ----
__global__ void k_cscatter(const int* __restrict__ row, const int* __restrict__ col,
                           int* __restrict__ gcur, unsigned* __restrict__ E) {
    __shared__ int lhist[NB];
    __shared__ int lbase[NB];
    for (int i = threadIdx.x; i < NB; i += 256) lhist[i] = 0;
    __syncthreads();
    int base = blockIdx.x * 8192;
    #pragma unroll
    for (int k = 0; k < 32; ++k) {
        int e = base + k * 256 + threadIdx.x;
        if (e < EDGES) atomicAdd(&lhist[col[e] >> 8], 1);
    }
    __syncthreads();
    for (int i = threadIdx.x; i < NB; i += 256) {
        int c = lhist[i];
        lbase[i] = c ? atomicAdd(&gcur[i], c) : 0;
        lhist[i] = 0;                       // reuse as local cursor
    }
    __syncthreads();
    #pragma unroll
    for (int k = 0; k < 32; ++k) {
        int e = base + k * 256 + threadIdx.x;
        if (e < EDGES) {
            int c = col[e];
            int b = c >> 8;
            int r = atomicAdd(&lhist[b], 1);
            E[lbase[b] + r] = ((unsigned)(c & 255) << 18) | (unsigned)row[e];
        }
    }
}

// ---- pass C: fine sort within one bucket; emits rowptr, dis, and fp8 y0 ----
__global__ void k_fsort(const unsigned* __restrict__ E, const int* __restrict__ cbase,
                        const float* __restrict__ emb, int* __restrict__ src_s,
                        int* __restrict__ rowptr, float* __restrict__ dis,
                        unsigned* __restrict__ y0) {
    __shared__ unsigned ebuf[CAP];
    __shared__ int hist[256];
    __shared__ int curs[256];
    __shared__ float sdis[256];
    int b = blockIdx.x;
    int base = cbase[b], end = cbase[b + 1];
    int cnt = end - base;
    int t = threadIdx.x;
    hist[t] = 0;
    __syncthreads();
    for (int i = t; i < cnt; i += 256) {
        unsigned p = E[base + i];
        if (i < CAP) ebuf[i] = p;
        atomicAdd(&hist[p >> 18], 1);
    }
    __syncthreads();
    int v = hist[t];
    int inc = v;
    #pragma unroll
    for (int o = 1; o < 256; o <<= 1) {
        int tmp = (t >= o) ? hist[t - o] : 0;
        __syncthreads();
        hist[t] = inc = inc + tmp;
        __syncthreads();
    }
    int ex = inc - v;
    curs[t] = ex;
    int node = (b << 8) + t;
    float dv = (node < NODES && v > 0) ? rsqrtf((float)v) : 0.0f;
    sdis[t] = dv;
    if (node < NODES) {
        rowptr[node] = base + ex;
        dis[node] = dv;
    }
    if (b == NB - 1 && t == 0) rowptr[NODES] = EDGES;
    __syncthreads();
    for (int i = t; i < cnt; i += 256) {
        unsigned p = (i < CAP) ? ebuf[i] : E[base + i];
        int c = p >> 18;
        int r = atomicAdd(&curs[c], 1);
        src_s[base + r] = (int)(p & 0x3FFFFu);
    }
    // fused prep: y0 = fp8(YSCALE * dis ⊙ emb), 16 dwords (64 fp8) per node
    int nbase = b << 8;
    for (int i = t; i < 4096; i += 256) {
        int nl = i >> 4, w = i & 15;
        int n2 = nbase + nl;
        if (n2 < NODES) {
            float4 e4 = ((const float4*)emb)[(n2 << 4) + w];
            float dS = sdis[nl] * YSCALE;
            int p = __builtin_amdgcn_cvt_pk_fp8_f32(e4.x * dS, e4.y * dS, 0, false);
            p = __builtin_amdgcn_cvt_pk_fp8_f32(e4.z * dS, e4.w * dS, p, true);
            y0[(n2 << 4) + w] = (unsigned)p;
        }
    }
}

__device__ __forceinline__ void acc_fp8(f32x4& A, unsigned d) {
    f32x2 lo = __builtin_amdgcn_cvt_pk_f32_fp8((int)d, false);
    f32x2 hi = __builtin_amdgcn_cvt_pk_f32_fp8((int)d, true);
    A.x += lo.x; A.y += lo.y; A.z += hi.x; A.w += hi.y;
}

// Edge-sum core, quarter-wave: lane group g=lane>>4 takes edge j+g, lane q=lane&15
// owns dims {4q..4q+3} (one dword = 4 fp8). All __shfl uniform across 64 lanes.
// After the xor-reduce every lane holds the FULL row sum for its 4 dims.
__device__ __forceinline__ f32x4 edge_sum8(const unsigned* __restrict__ y8,
                                           const int* __restrict__ src_s,
                                           int jb, int deg, int lane) {
    int g = lane >> 4;
    int q = lane & 15;
    f32x4 A0 = {0.f,0.f,0.f,0.f}, A1 = {0.f,0.f,0.f,0.f},
          A2 = {0.f,0.f,0.f,0.f}, A3 = {0.f,0.f,0.f,0.f};
    for (int base = 0; base < deg; base += 64) {
        int rem = deg - base;
        int m   = rem < 64 ? rem : 64;
        int idx = (base + lane < deg) ? src_s[jb + base + lane] : 0;
        int j = 0;
        for (; j + 16 <= m; j += 16) {
            int s0 = __shfl(idx, j +  0 + g);
            int s1 = __shfl(idx, j +  4 + g);
            int s2 = __shfl(idx, j +  8 + g);
            int s3 = __shfl(idx, j + 12 + g);
            unsigned d0 = y8[(s0 << 4) + q];
            unsigned d1 = y8[(s1 << 4) + q];
            unsigned d2 = y8[(s2 << 4) + q];
            unsigned d3 = y8[(s3 << 4) + q];
            acc_fp8(A0, d0); acc_fp8(A1, d1); acc_fp8(A2, d2); acc_fp8(A3, d3);
        }
        for (; j + 4 <= m; j += 4) {
            int s = __shfl(idx, j + g);
            acc_fp8(A0, y8[(s << 4) + q]);
        }
        if (j < m) {                         // 1..3 leftover edges
            int left = m - j;
            int s = __shfl(idx, j + g);      // uniform shuffle (may over-read, discarded)
            if (g < left) acc_fp8(A0, y8[(s << 4) + q]);
        }
    }
    f32x4 A;
    A.x = (A0.x + A1.x) + (A2.x + A3.x);
    A.y = (A0.y + A1.y) + (A2.y + A3.y);
    A.z = (A0.z + A1.z) + (A2.z + A3.z);
    A.w = (A0.w + A1.w) + (A2.w + A3.w);
    A.x += __shfl_xor(A.x, 16); A.x += __shfl_xor(A.x, 32);
    A.y += __shfl_xor(A.y, 16); A.y += __shfl_xor(A.y, 32);
    A.z += __shfl_xor(A.z, 16); A.z += __shfl_xor(A.z, 32);
    A.w += __shfl_xor(A.w, 16); A.w += __shfl_xor(A.w, 32);
    return A;
}

// ---- layers 1,2: yn = fp8(dis^2 * sum y[src]) (scaled), plus f16 side-copy ----
__global__ void k_gather(const unsigned* __restrict__ y8, const int* __restrict__ src_s,
                         const int* __restrict__ rowptr, const float* __restrict__ dis,
                         unsigned* __restrict__ yn8, uint2* __restrict__ yn16) {
    int n    = (blockIdx.x << 2) + (threadIdx.x >> 6);
    int lane = threadIdx.x & 63;
    if (n >= NODES) return;
    int jb  = rowptr[n];
    int deg = rowptr[n + 1] - jb;
    f32x4 A = edge_sum8(y8, src_s, jb, deg, lane);
    float dd = dis[n]; dd = dd * dd;
    A.x *= dd; A.y *= dd; A.z *= dd; A.w *= dd;
    if (lane < 16) {
        int o = (n << 4) + lane;
        int p = __builtin_amdgcn_cvt_pk_fp8_f32(A.x, A.y, 0, false);
        p = __builtin_amdgcn_cvt_pk_fp8_f32(A.z, A.w, p, true);
        yn8[o] = (unsigned)p;
        __half2 h0 = __floats2half2_rn(A.x, A.y);
        __half2 h1 = __floats2half2_rn(A.z, A.w);
        uint2 u;
        u.x = *reinterpret_cast<unsigned*>(&h0);
        u.y = *reinterpret_cast<unsigned*>(&h1);
        yn16[o] = u;
    }
}

// ---- layer 3 fused with combine + item L2-normalize ----
// x3 = d*(sum fp8 y2)/S;  direct y1,y2 terms come from the clean f16 copies.
__global__ void k_gather3(const unsigned* __restrict__ y2_8,
                          const uint2* __restrict__ y1_16, const uint2* __restrict__ y2_16,
                          const float* __restrict__ emb, const int* __restrict__ src_s,
                          const int* __restrict__ rowptr, const float* __restrict__ dis,
                          const float* __restrict__ alpha, const float* __restrict__ sf,
                          float* __restrict__ acc) {
    int n    = (blockIdx.x << 2) + (threadIdx.x >> 6);
    int lane = threadIdx.x & 63;
    if (n >= NODES) return;
    int q  = lane & 15;
    int jb = rowptr[n];
    int deg = rowptr[n + 1] - jb;
    f32x4 A = edge_sum8(y2_8, src_s, jb, deg, lane);
    float d   = dis[n];
    float inv = d > 0.0f ? 1.0f / d : 0.0f;
    int   o   = (n << 4) + q;
    float4 e4 = ((const float4*)emb)[o];
    uint2 u1 = y1_16[o], u2 = y2_16[o];
    __half2 h10 = *reinterpret_cast<__half2*>(&u1.x);
    __half2 h11 = *reinterpret_cast<__half2*>(&u1.y);
    __half2 h20 = *reinterpret_cast<__half2*>(&u2.x);
    __half2 h21 = *reinterpret_cast<__half2*>(&u2.y);
    float c0 = alpha[0];
    float c1 = alpha[1] * inv * IYSCALE;
    float c2 = alpha[2] * inv * IYSCALE;
    float c3 = alpha[3] * d   * IYSCALE;
    float4 v;
    v.x = c0 * e4.x + c1 * __low2float(h10)  + c2 * __low2float(h20)  + c3 * A.x;
    v.y = c0 * e4.y + c1 * __high2float(h10) + c2 * __high2float(h20) + c3 * A.y;
    v.z = c0 * e4.z + c1 * __low2float(h11)  + c2 * __low2float(h21)  + c3 * A.z;
    v.w = c0 * e4.w + c1 * __high2float(h11) + c2 * __high2float(h21) + c3 * A.w;
    if (n >= NUSERS) {
        float ss = v.x * v.x + v.y * v.y + v.z * v.z + v.w * v.w;
        #pragma unroll
        for (int m = 1; m < 16; m <<= 1) ss += __shfl_xor(ss, m);
        float nrm = fmaxf(sqrtf(ss), 1e-12f);
        float sc  = sf[0] / nrm;
        v.x *= sc; v.y *= sc; v.z *= sc; v.w *= sc;
    }
    if (lane < 16) ((float4*)acc)[o] = v;
}

// ---- rank[k] = dot(acc[src[k]], acc[dst[k]]) : 32 lanes per pair, float2 ----
__global__ void k_rank(const float* __restrict__ acc, const int* __restrict__ eli,
                       float* __restrict__ rank) {
    int k    = (blockIdx.x << 3) + (threadIdx.x >> 5);
    int q    = threadIdx.x & 31;
    if (k >= LABELS) return;
    int s = eli[k];
    int d = eli[LABELS + k];
    float2 vs = ((const float2*)acc)[(s << 5) + q];
    float2 vd = ((const float2*)acc)[(d << 5) + q];
    float p = vs.x * vd.x + vs.y * vd.y;
    #pragma unroll
    for (int m = 1; m < 32; m <<= 1) p += __shfl_xor(p, m);
    if (q == 0) rank[k] = p;
}

// ---- out[which][i][j] = rank[which*4096+j] + beta[eli[LABELS+which*4096+i]] ----
__global__ void k_final(const float* __restrict__ rank, const float* __restrict__ beta,
                        const int* __restrict__ eli, float* __restrict__ out) {
    int t     = blockIdx.x * blockDim.x + threadIdx.x;   // [0, 2^23)
    int which = t >> 22;
    int tt    = t & ((1 << 22) - 1);
    int i     = tt >> 10;
    int j4    = (tt & 1023) << 2;
    int item  = eli[LABELS + (which << 12) + i];
    float b   = beta[item];
    const float* rk = rank + (which << 12);
    float4 r = *reinterpret_cast<const float4*>(rk + j4);
    f32x4 vv = { r.x + b, r.y + b, r.z + b, r.w + b };
    __builtin_nontemporal_store(vv, reinterpret_cast<f32x4*>(out + ((size_t)t << 2)));
}

extern "C" void kernel_launch(void* const* d_in, const int* in_sizes, int n_in,
                              void* d_out, int out_size, void* d_ws, size_t ws_size,
                              hipStream_t stream) {
    const float* emb   = (const float*)d_in[0];
    const float* beta  = (const float*)d_in[1];
    const float* alpha = (const float*)d_in[2];
    const int*   eidx  = (const int*)d_in[3];
    const int*   eli   = (const int*)d_in[4];
    const float* sf    = (const float*)d_in[7];

    const int* row = eidx;
    const int* col = eidx + EDGES;

    // ---- workspace layout (4-byte units) ----
    char* ws = (char*)d_ws;
    int*      rowptr = (int*)     (ws);                   // NODES+1
    float*    dis    = (float*)   (ws + 151552u * 4);     // NODES
    int*      chist  = (int*)     (ws + 303104u * 4);     // NB (pad 1024)
    int*      cbase  = (int*)     (ws + 304128u * 4);     // NB+1 (pad 1024)
    int*      gcur   = (int*)     (ws + 305152u * 4);     // NB (pad 1024)
    float*    rank   = (float*)   (ws + 306176u * 4);     // LABELS
    unsigned* E      = (unsigned*)(ws + 315392u * 4);     // EDGES
    int*      src_s  = (int*)     (ws + 4315392u * 4);    // EDGES

    // d_out tail layout (f32/dword units): acc, fp8 y ×3, f16 copies ×2
    float*    acc   = (float*)d_out;                        // 9.6M f32
    unsigned* od    = (unsigned*)d_out;
    unsigned* Y0_8  = od + 10485760u;                       // 2.4M dwords
    unsigned* Y1_8  = od + 13107200u;
    unsigned* Y2_8  = od + 15728640u;
    uint2*    Y1_16 = (uint2*)(od + 18350080u);             // 2.4M uint2
    uint2*    Y2_16 = (uint2*)(od + 23592960u);             // ends < 33.5M

    const int NN4 = (NODES + 3) / 4;

    // ---- CSR build (two-level counting sort; emits rowptr + dis + fp8 y0) ----
    hipMemsetAsync(chist, 0, 1024 * sizeof(int), stream);
    k_chist<<<(EDGES + 4095) / 4096, 256, 0, stream>>>(col, chist);
    k_scanB<<<1, 64, 0, stream>>>(chist, cbase, gcur);
    k_cscatter<<<(EDGES + 8191) / 8192, 256, 0, stream>>>(row, col, gcur, E);
    k_fsort<<<NB, 256, 0, stream>>>(E, cbase, emb, src_s, rowptr, dis, Y0_8);

    // ---- propagation (fp8 y-space, f32 accumulate) ----
    k_gather<<<NN4, 256, 0, stream>>>(Y0_8, src_s, rowptr, dis, Y1_8, Y1_16);
    k_gather<<<NN4, 256, 0, stream>>>(Y1_8, src_s, rowptr, dis, Y2_8, Y2_16);
    k_gather3<<<NN4, 256, 0, stream>>>(Y2_8, Y1_16, Y2_16, emb, src_s, rowptr, dis,
                                       alpha, sf, acc);

    // ---- epilogue ----
    k_rank<<<LABELS / 8, 256, 0, stream>>>(acc, eli, rank);
    k_final<<<(1 << 23) / 256, 256, 0, stream>>>(rank, beta, eli, (float*)d_out);
}

// Round 12
// 348.353 us; speedup vs baseline: 1.1870x; 1.0406x over previous
//
#include <hip/hip_runtime.h>
#include <hip/hip_bf16.h>
#include <hip/hip_fp16.h>
#include <cstdint>

#define NODES   150000
#define DIM     64
#define EDGES   4000000
#define LABELS  8192
#define NUSERS  100000
#define NITEMS  50000

#define NB2     293          // ceil(NODES/512) coarse buckets of 512 nodes
#define BCAP    16384        // per-bucket capacity (mean 13653, +23 sigma)
#define CAP2    14336        // LDS ebuf staging (mean +5.9 sigma; overflow re-reads E)

#define YSCALE  1024.0f      // power-of-two pre-scale so y fits e4m3 normal range
#define IYSCALE (1.0f / 1024.0f)

typedef float f32x4 __attribute__((ext_vector_type(4)));
typedef float f32x2 __attribute__((ext_vector_type(2)));

// ---- init per-bucket cursors to fixed bases (replaces chist+scanB) ----
__global__ void k_init(int* __restrict__ gcur) {
    int i = blockIdx.x * blockDim.x + threadIdx.x;
    if (i < NB2) gcur[i] = i * BCAP;
}

// ---- coarse scatter into fixed-capacity bucket regions ----
__global__ void k_cscatter(const int* __restrict__ row, const int* __restrict__ col,
                           int* __restrict__ gcur, unsigned* __restrict__ E) {
    __shared__ int lhist[NB2];
    __shared__ int lbase[NB2];
    for (int i = threadIdx.x; i < NB2; i += 256) lhist[i] = 0;
    __syncthreads();
    int base = blockIdx.x * 8192;
    #pragma unroll
    for (int k = 0; k < 32; ++k) {
        int e = base + k * 256 + threadIdx.x;
        if (e < EDGES) atomicAdd(&lhist[col[e] >> 9], 1);
    }
    __syncthreads();
    for (int i = threadIdx.x; i < NB2; i += 256) {
        int c = lhist[i];
        lbase[i] = c ? atomicAdd(&gcur[i], c) : 0;
        lhist[i] = 0;                       // reuse as local cursor
    }
    __syncthreads();
    #pragma unroll
    for (int k = 0; k < 32; ++k) {
        int e = base + k * 256 + threadIdx.x;
        if (e < EDGES) {
            int c = col[e];
            int b = c >> 9;
            int r = atomicAdd(&lhist[b], 1);
            E[lbase[b] + r] = ((unsigned)(c & 511) << 18) | (unsigned)row[e];
        }
    }
}

// ---- fine sort within one 512-node bucket; emits jpack, dis, fp8 y0 ----
__global__ void k_fsort(const unsigned* __restrict__ E, const int* __restrict__ gcur,
                        const float* __restrict__ emb, int* __restrict__ src_s,
                        int* __restrict__ jpack, float* __restrict__ dis,
                        unsigned* __restrict__ y0) {
    __shared__ unsigned ebuf[CAP2];
    __shared__ int hist[512];
    __shared__ int curs[512];
    __shared__ float sdis[512];
    int b = blockIdx.x;
    int base = b * BCAP;
    int cnt = gcur[b] - base;
    int t = threadIdx.x;
    hist[t] = 0;
    __syncthreads();
    for (int i = t; i < cnt; i += 512) {
        unsigned p = E[base + i];
        if (i < CAP2) ebuf[i] = p;
        atomicAdd(&hist[p >> 18], 1);
    }
    __syncthreads();
    int v = hist[t];
    int inc = v;
    #pragma unroll
    for (int o = 1; o < 512; o <<= 1) {
        int tmp = (t >= o) ? hist[t - o] : 0;
        __syncthreads();
        hist[t] = inc = inc + tmp;
        __syncthreads();
    }
    int ex = inc - v;
    curs[t] = ex;
    int node = (b << 9) + t;
    float dv = (node < NODES && v > 0) ? rsqrtf((float)v) : 0.0f;
    sdis[t] = dv;
    if (node < NODES) {
        jpack[node] = (base + ex) | (v << 23);   // jb in low 23 bits, deg above
        dis[node] = dv;
    }
    __syncthreads();
    for (int i = t; i < cnt; i += 512) {
        unsigned p = (i < CAP2) ? ebuf[i] : E[base + i];
        int c = p >> 18;
        int r = atomicAdd(&curs[c], 1);
        src_s[base + r] = (int)(p & 0x3FFFFu);
    }
    // fused prep: y0 = fp8(YSCALE * dis ⊙ emb) for this bucket's 512 nodes
    int nbase = b << 9;
    for (int i = t; i < 8192; i += 512) {
        int nl = i >> 4, w = i & 15;
        int n2 = nbase + nl;
        if (n2 < NODES) {
            float4 e4 = ((const float4*)emb)[(n2 << 4) + w];
            float dS = sdis[nl] * YSCALE;
            int p = __builtin_amdgcn_cvt_pk_fp8_f32(e4.x * dS, e4.y * dS, 0, false);
            p = __builtin_amdgcn_cvt_pk_fp8_f32(e4.z * dS, e4.w * dS, p, true);
            y0[(n2 << 4) + w] = (unsigned)p;
        }
    }
}

__device__ __forceinline__ void acc_fp8(f32x4& A, unsigned d) {
    f32x2 lo = __builtin_amdgcn_cvt_pk_f32_fp8((int)d, false);
    f32x2 hi = __builtin_amdgcn_cvt_pk_f32_fp8((int)d, true);
    A.x += lo.x; A.y += lo.y; A.z += hi.x; A.w += hi.y;
}

// Edge-sum core, quarter-wave: lane group g=lane>>4 takes edge j+g, lane q=lane&15
// owns dims {4q..4q+3} (one dword = 4 fp8). All __shfl uniform across 64 lanes.
__device__ __forceinline__ f32x4 edge_sum8(const unsigned* __restrict__ y8,
                                           const int* __restrict__ src_s,
                                           int jb, int deg, int lane) {
    int g = lane >> 4;
    int q = lane & 15;
    f32x4 A0 = {0.f,0.f,0.f,0.f}, A1 = {0.f,0.f,0.f,0.f},
          A2 = {0.f,0.f,0.f,0.f}, A3 = {0.f,0.f,0.f,0.f};
    for (int base = 0; base < deg; base += 64) {
        int rem = deg - base;
        int m   = rem < 64 ? rem : 64;
        int idx = (base + lane < deg) ? src_s[jb + base + lane] : 0;
        int j = 0;
        for (; j + 16 <= m; j += 16) {
            int s0 = __shfl(idx, j +  0 + g);
            int s1 = __shfl(idx, j +  4 + g);
            int s2 = __shfl(idx, j +  8 + g);
            int s3 = __shfl(idx, j + 12 + g);
            unsigned d0 = y8[(s0 << 4) + q];
            unsigned d1 = y8[(s1 << 4) + q];
            unsigned d2 = y8[(s2 << 4) + q];
            unsigned d3 = y8[(s3 << 4) + q];
            acc_fp8(A0, d0); acc_fp8(A1, d1); acc_fp8(A2, d2); acc_fp8(A3, d3);
        }
        for (; j + 4 <= m; j += 4) {
            int s = __shfl(idx, j + g);
            acc_fp8(A0, y8[(s << 4) + q]);
        }
        if (j < m) {                         // 1..3 leftover edges
            int left = m - j;
            int s = __shfl(idx, j + g);      // uniform shuffle
            if (g < left) acc_fp8(A0, y8[(s << 4) + q]);
        }
    }
    f32x4 A;
    A.x = (A0.x + A1.x) + (A2.x + A3.x);
    A.y = (A0.y + A1.y) + (A2.y + A3.y);
    A.z = (A0.z + A1.z) + (A2.z + A3.z);
    A.w = (A0.w + A1.w) + (A2.w + A3.w);
    A.x += __shfl_xor(A.x, 16); A.x += __shfl_xor(A.x, 32);
    A.y += __shfl_xor(A.y, 16); A.y += __shfl_xor(A.y, 32);
    A.z += __shfl_xor(A.z, 16); A.z += __shfl_xor(A.z, 32);
    A.w += __shfl_xor(A.w, 16); A.w += __shfl_xor(A.w, 32);
    return A;
}

// ---- layers 1,2: yn = fp8(dis^2 * sum y[src]) (scaled) ----
__global__ void k_gather(const unsigned* __restrict__ y8, const int* __restrict__ src_s,
                         const int* __restrict__ jpack, const float* __restrict__ dis,
                         unsigned* __restrict__ yn8) {
    int n    = (blockIdx.x << 2) + (threadIdx.x >> 6);
    int lane = threadIdx.x & 63;
    if (n >= NODES) return;
    unsigned jp = (unsigned)jpack[n];
    int jb  = jp & 0x7FFFFF;
    int deg = jp >> 23;
    f32x4 A = edge_sum8(y8, src_s, jb, deg, lane);
    float dd = dis[n]; dd = dd * dd;
    if (lane < 16) {
        int o = (n << 4) + lane;
        int p = __builtin_amdgcn_cvt_pk_fp8_f32(A.x * dd, A.y * dd, 0, false);
        p = __builtin_amdgcn_cvt_pk_fp8_f32(A.z * dd, A.w * dd, p, true);
        yn8[o] = (unsigned)p;
    }
}

// ---- layer 3 fused with combine + item L2-normalize ----
__global__ void k_gather3(const unsigned* __restrict__ y2_8,
                          const unsigned* __restrict__ y1_8,
                          const float* __restrict__ emb, const int* __restrict__ src_s,
                          const int* __restrict__ jpack, const float* __restrict__ dis,
                          const float* __restrict__ alpha, const float* __restrict__ sf,
                          float* __restrict__ acc) {
    int n    = (blockIdx.x << 2) + (threadIdx.x >> 6);
    int lane = threadIdx.x & 63;
    if (n >= NODES) return;
    int q  = lane & 15;
    unsigned jp = (unsigned)jpack[n];
    int jb  = jp & 0x7FFFFF;
    int deg = jp >> 23;
    f32x4 A = edge_sum8(y2_8, src_s, jb, deg, lane);
    float d   = dis[n];
    float inv = d > 0.0f ? 1.0f / d : 0.0f;
    int   o   = (n << 4) + q;
    float4 e4 = ((const float4*)emb)[o];
    unsigned u1 = y1_8[o], u2 = y2_8[o];
    f32x2 y1lo = __builtin_amdgcn_cvt_pk_f32_fp8((int)u1, false);
    f32x2 y1hi = __builtin_amdgcn_cvt_pk_f32_fp8((int)u1, true);
    f32x2 y2lo = __builtin_amdgcn_cvt_pk_f32_fp8((int)u2, false);
    f32x2 y2hi = __builtin_amdgcn_cvt_pk_f32_fp8((int)u2, true);
    float c0 = alpha[0];
    float c1 = alpha[1] * inv * IYSCALE;
    float c2 = alpha[2] * inv * IYSCALE;
    float c3 = alpha[3] * d   * IYSCALE;
    float4 v;
    v.x = c0 * e4.x + c1 * y1lo.x + c2 * y2lo.x + c3 * A.x;
    v.y = c0 * e4.y + c1 * y1lo.y + c2 * y2lo.y + c3 * A.y;
    v.z = c0 * e4.z + c1 * y1hi.x + c2 * y2hi.x + c3 * A.z;
    v.w = c0 * e4.w + c1 * y1hi.y + c2 * y2hi.y + c3 * A.w;
    if (n >= NUSERS) {
        float ss = v.x * v.x + v.y * v.y + v.z * v.z + v.w * v.w;
        #pragma unroll
        for (int m = 1; m < 16; m <<= 1) ss += __shfl_xor(ss, m);
        float nrm = fmaxf(sqrtf(ss), 1e-12f);
        float sc  = sf[0] / nrm;
        v.x *= sc; v.y *= sc; v.z *= sc; v.w *= sc;
    }
    if (lane < 16) ((float4*)acc)[o] = v;
}

// ---- rank[k] = dot(acc[src[k]], acc[dst[k]]) : 32 lanes per pair, float2 ----
__global__ void k_rank(const float* __restrict__ acc, const int* __restrict__ eli,
                       float* __restrict__ rank) {
    int k    = (blockIdx.x << 3) + (threadIdx.x >> 5);
    int q    = threadIdx.x & 31;
    if (k >= LABELS) return;
    int s = eli[k];
    int d = eli[LABELS + k];
    float2 vs = ((const float2*)acc)[(s << 5) + q];
    float2 vd = ((const float2*)acc)[(d << 5) + q];
    float p = vs.x * vd.x + vs.y * vd.y;
    #pragma unroll
    for (int m = 1; m < 32; m <<= 1) p += __shfl_xor(p, m);
    if (q == 0) rank[k] = p;
}

// ---- out[which][i][j] = rank[which*4096+j] + beta[eli[LABELS+which*4096+i]] ----
__global__ void k_final(const float* __restrict__ rank, const float* __restrict__ beta,
                        const int* __restrict__ eli, float* __restrict__ out) {
    int t     = blockIdx.x * blockDim.x + threadIdx.x;   // [0, 2^23)
    int which = t >> 22;
    int tt    = t & ((1 << 22) - 1);
    int i     = tt >> 10;
    int j4    = (tt & 1023) << 2;
    int item  = eli[LABELS + (which << 12) + i];
    float b   = beta[item];
    const float* rk = rank + (which << 12);
    float4 r = *reinterpret_cast<const float4*>(rk + j4);
    f32x4 vv = { r.x + b, r.y + b, r.z + b, r.w + b };
    __builtin_nontemporal_store(vv, reinterpret_cast<f32x4*>(out + ((size_t)t << 2)));
}

extern "C" void kernel_launch(void* const* d_in, const int* in_sizes, int n_in,
                              void* d_out, int out_size, void* d_ws, size_t ws_size,
                              hipStream_t stream) {
    const float* emb   = (const float*)d_in[0];
    const float* beta  = (const float*)d_in[1];
    const float* alpha = (const float*)d_in[2];
    const int*   eidx  = (const int*)d_in[3];
    const int*   eli   = (const int*)d_in[4];
    const float* sf    = (const float*)d_in[7];

    const int* row = eidx;
    const int* col = eidx + EDGES;

    // ---- workspace layout (4-byte units) ----
    char* ws = (char*)d_ws;
    int*   jpack = (int*)  (ws);                   // NODES
    float* dis   = (float*)(ws + 151552u * 4);     // NODES
    int*   gcur  = (int*)  (ws + 303104u * 4);     // NB2 (pad 1024)
    float* rank  = (float*)(ws + 304128u * 4);     // LABELS

    // d_out tail layout (dword units): acc, fp8 y ×3, E, src_s
    float*    acc   = (float*)d_out;                 // 9.6M f32
    unsigned* od    = (unsigned*)d_out;
    unsigned* Y0_8  = od + 10485760u;                // 2.4M dwords each
    unsigned* Y1_8  = od + 13107200u;
    unsigned* Y2_8  = od + 15728640u;
    unsigned* E     = od + 18350080u;                // NB2*BCAP = 4800512 dwords
    int*      src_s = (int*)(od + 23592960u);        // 4800512 dwords, ends < 28.4M

    const int NN4 = (NODES + 3) / 4;

    // ---- CSR build (fixed-capacity buckets; no chist/scan pass) ----
    k_init<<<2, 256, 0, stream>>>(gcur);
    k_cscatter<<<(EDGES + 8191) / 8192, 256, 0, stream>>>(row, col, gcur, E);
    k_fsort<<<NB2, 512, 0, stream>>>(E, gcur, emb, src_s, jpack, dis, Y0_8);

    // ---- propagation (fp8 y-space, f32 accumulate) ----
    k_gather<<<NN4, 256, 0, stream>>>(Y0_8, src_s, jpack, dis, Y1_8);
    k_gather<<<NN4, 256, 0, stream>>>(Y1_8, src_s, jpack, dis, Y2_8);
    k_gather3<<<NN4, 256, 0, stream>>>(Y2_8, Y1_8, emb, src_s, jpack, dis,
                                       alpha, sf, acc);

    // ---- epilogue ----
    k_rank<<<LABELS / 8, 256, 0, stream>>>(acc, eli, rank);
    k_final<<<(1 << 23) / 256, 256, 0, stream>>>(rank, beta, eli, (float*)d_out);
}

// Round 13
// 331.982 us; speedup vs baseline: 1.2456x; 1.0493x over previous
//
#include <hip/hip_runtime.h>
#include <hip/hip_bf16.h>
#include <hip/hip_fp16.h>
#include <cstdint>

#define NODES   150000
#define DIM     64
#define EDGES   4000000
#define LABELS  8192
#define NUSERS  100000
#define NITEMS  50000

#define NB2     293          // ceil(NODES/512) coarse buckets of 512 nodes
#define BCAP    16384        // per-bucket capacity (mean 13653, +23 sigma)
#define CAP2    14336        // LDS ebuf staging (mean +5.9 sigma; overflow re-reads E)

#define YSCALE  1024.0f      // power-of-two pre-scale so y fits e4m3 normal range
#define IYSCALE (1.0f / 1024.0f)

typedef float f32x4 __attribute__((ext_vector_type(4)));
typedef float f32x2 __attribute__((ext_vector_type(2)));

// ---- init per-bucket cursors to fixed bases (replaces chist+scanB) ----
__global__ void k_init(int* __restrict__ gcur) {
    int i = blockIdx.x * blockDim.x + threadIdx.x;
    if (i < NB2) gcur[i] = i * BCAP;
}

// ---- coarse scatter into fixed-capacity bucket regions ----
// 1024 threads/block (16 waves -> latency hiding), 8 edges/thread in registers.
__global__ void __launch_bounds__(1024, 2)
k_cscatter(const int* __restrict__ row, const int* __restrict__ col,
           int* __restrict__ gcur, unsigned* __restrict__ E) {
    __shared__ int lhist[NB2];
    __shared__ int lbase[NB2];
    for (int i = threadIdx.x; i < NB2; i += 1024) lhist[i] = 0;
    __syncthreads();
    int base = blockIdx.x * 8192;
    int c8[8], r8[8];
    #pragma unroll
    for (int k = 0; k < 8; ++k) {
        int e = base + k * 1024 + threadIdx.x;
        if (e < EDGES) {
            c8[k] = col[e];
            r8[k] = row[e];
            atomicAdd(&lhist[c8[k] >> 9], 1);
        } else {
            c8[k] = -1; r8[k] = 0;
        }
    }
    __syncthreads();
    for (int i = threadIdx.x; i < NB2; i += 1024) {
        int c = lhist[i];
        lbase[i] = c ? atomicAdd(&gcur[i], c) : 0;
        lhist[i] = 0;                       // reuse as local cursor
    }
    __syncthreads();
    #pragma unroll
    for (int k = 0; k < 8; ++k) {
        if (c8[k] >= 0) {
            int b = c8[k] >> 9;
            int r = atomicAdd(&lhist[b], 1);
            E[lbase[b] + r] = ((unsigned)(c8[k] & 511) << 18) | (unsigned)r8[k];
        }
    }
}

// ---- fine sort within one 512-node bucket; emits jpack, dis, fp8 y0 ----
__global__ void k_fsort(const unsigned* __restrict__ E, const int* __restrict__ gcur,
                        const float* __restrict__ emb, int* __restrict__ src_s,
                        int* __restrict__ jpack, float* __restrict__ dis,
                        unsigned* __restrict__ y0) {
    __shared__ unsigned ebuf[CAP2];
    __shared__ int hist[512];
    __shared__ int curs[512];
    __shared__ float sdis[512];
    int b = blockIdx.x;
    int base = b * BCAP;
    int cnt = gcur[b] - base;
    int t = threadIdx.x;
    hist[t] = 0;
    __syncthreads();
    for (int i = t; i < cnt; i += 512) {
        unsigned p = E[base + i];
        if (i < CAP2) ebuf[i] = p;
        atomicAdd(&hist[p >> 18], 1);
    }
    __syncthreads();
    int v = hist[t];
    int inc = v;
    #pragma unroll
    for (int o = 1; o < 512; o <<= 1) {
        int tmp = (t >= o) ? hist[t - o] : 0;
        __syncthreads();
        hist[t] = inc = inc + tmp;
        __syncthreads();
    }
    int ex = inc - v;
    curs[t] = ex;
    int node = (b << 9) + t;
    float dv = (node < NODES && v > 0) ? rsqrtf((float)v) : 0.0f;
    sdis[t] = dv;
    if (node < NODES) {
        jpack[node] = (base + ex) | (v << 23);   // jb in low 23 bits, deg above
        dis[node] = dv;
    }
    __syncthreads();
    for (int i = t; i < cnt; i += 512) {
        unsigned p = (i < CAP2) ? ebuf[i] : E[base + i];
        int c = p >> 18;
        int r = atomicAdd(&curs[c], 1);
        src_s[base + r] = (int)(p & 0x3FFFFu);
    }
    // fused prep: y0 = fp8(YSCALE * dis ⊙ emb) for this bucket's 512 nodes
    int nbase = b << 9;
    for (int i = t; i < 8192; i += 512) {
        int nl = i >> 4, w = i & 15;
        int n2 = nbase + nl;
        if (n2 < NODES) {
            float4 e4 = ((const float4*)emb)[(n2 << 4) + w];
            float dS = sdis[nl] * YSCALE;
            int p = __builtin_amdgcn_cvt_pk_fp8_f32(e4.x * dS, e4.y * dS, 0, false);
            p = __builtin_amdgcn_cvt_pk_fp8_f32(e4.z * dS, e4.w * dS, p, true);
            y0[(n2 << 4) + w] = (unsigned)p;
        }
    }
}

__device__ __forceinline__ void acc_fp8(f32x4& A, unsigned d) {
    f32x2 lo = __builtin_amdgcn_cvt_pk_f32_fp8((int)d, false);
    f32x2 hi = __builtin_amdgcn_cvt_pk_f32_fp8((int)d, true);
    A.x += lo.x; A.y += lo.y; A.z += hi.x; A.w += hi.y;
}

// Edge-sum core, quarter-wave: lane group g=lane>>4 takes edge j+g, lane q=lane&15
// owns dims {4q..4q+3} (one dword = 4 fp8). All __shfl uniform across 64 lanes.
__device__ __forceinline__ f32x4 edge_sum8(const unsigned* __restrict__ y8,
                                           const int* __restrict__ src_s,
                                           int jb, int deg, int lane) {
    int g = lane >> 4;
    int q = lane & 15;
    f32x4 A0 = {0.f,0.f,0.f,0.f}, A1 = {0.f,0.f,0.f,0.f},
          A2 = {0.f,0.f,0.f,0.f}, A3 = {0.f,0.f,0.f,0.f};
    for (int base = 0; base < deg; base += 64) {
        int rem = deg - base;
        int m   = rem < 64 ? rem : 64;
        int idx = (base + lane < deg) ? src_s[jb + base + lane] : 0;
        int j = 0;
        for (; j + 16 <= m; j += 16) {
            int s0 = __shfl(idx, j +  0 + g);
            int s1 = __shfl(idx, j +  4 + g);
            int s2 = __shfl(idx, j +  8 + g);
            int s3 = __shfl(idx, j + 12 + g);
            unsigned d0 = y8[(s0 << 4) + q];
            unsigned d1 = y8[(s1 << 4) + q];
            unsigned d2 = y8[(s2 << 4) + q];
            unsigned d3 = y8[(s3 << 4) + q];
            acc_fp8(A0, d0); acc_fp8(A1, d1); acc_fp8(A2, d2); acc_fp8(A3, d3);
        }
        for (; j + 4 <= m; j += 4) {
            int s = __shfl(idx, j + g);
            acc_fp8(A0, y8[(s << 4) + q]);
        }
        if (j < m) {                         // 1..3 leftover edges
            int left = m - j;
            int s = __shfl(idx, j + g);      // uniform shuffle
            if (g < left) acc_fp8(A0, y8[(s << 4) + q]);
        }
    }
    f32x4 A;
    A.x = (A0.x + A1.x) + (A2.x + A3.x);
    A.y = (A0.y + A1.y) + (A2.y + A3.y);
    A.z = (A0.z + A1.z) + (A2.z + A3.z);
    A.w = (A0.w + A1.w) + (A2.w + A3.w);
    A.x += __shfl_xor(A.x, 16); A.x += __shfl_xor(A.x, 32);
    A.y += __shfl_xor(A.y, 16); A.y += __shfl_xor(A.y, 32);
    A.z += __shfl_xor(A.z, 16); A.z += __shfl_xor(A.z, 32);
    A.w += __shfl_xor(A.w, 16); A.w += __shfl_xor(A.w, 32);
    return A;
}

// ---- layers 1,2: yn = fp8(dis^2 * sum y[src]) (scaled) ----
__global__ void k_gather(const unsigned* __restrict__ y8, const int* __restrict__ src_s,
                         const int* __restrict__ jpack, const float* __restrict__ dis,
                         unsigned* __restrict__ yn8) {
    int n    = (blockIdx.x << 2) + (threadIdx.x >> 6);
    int lane = threadIdx.x & 63;
    if (n >= NODES) return;
    unsigned jp = (unsigned)jpack[n];
    int jb  = jp & 0x7FFFFF;
    int deg = jp >> 23;
    f32x4 A = edge_sum8(y8, src_s, jb, deg, lane);
    float dd = dis[n]; dd = dd * dd;
    if (lane < 16) {
        int o = (n << 4) + lane;
        int p = __builtin_amdgcn_cvt_pk_fp8_f32(A.x * dd, A.y * dd, 0, false);
        p = __builtin_amdgcn_cvt_pk_fp8_f32(A.z * dd, A.w * dd, p, true);
        yn8[o] = (unsigned)p;
    }
}

// ---- layer 3 fused with combine + item L2-normalize ----
__global__ void k_gather3(const unsigned* __restrict__ y2_8,
                          const unsigned* __restrict__ y1_8,
                          const float* __restrict__ emb, const int* __restrict__ src_s,
                          const int* __restrict__ jpack, const float* __restrict__ dis,
                          const float* __restrict__ alpha, const float* __restrict__ sf,
                          float* __restrict__ acc) {
    int n    = (blockIdx.x << 2) + (threadIdx.x >> 6);
    int lane = threadIdx.x & 63;
    if (n >= NODES) return;
    int q  = lane & 15;
    unsigned jp = (unsigned)jpack[n];
    int jb  = jp & 0x7FFFFF;
    int deg = jp >> 23;
    f32x4 A = edge_sum8(y2_8, src_s, jb, deg, lane);
    float d   = dis[n];
    float inv = d > 0.0f ? 1.0f / d : 0.0f;
    int   o   = (n << 4) + q;
    float4 e4 = ((const float4*)emb)[o];
    unsigned u1 = y1_8[o], u2 = y2_8[o];
    f32x2 y1lo = __builtin_amdgcn_cvt_pk_f32_fp8((int)u1, false);
    f32x2 y1hi = __builtin_amdgcn_cvt_pk_f32_fp8((int)u1, true);
    f32x2 y2lo = __builtin_amdgcn_cvt_pk_f32_fp8((int)u2, false);
    f32x2 y2hi = __builtin_amdgcn_cvt_pk_f32_fp8((int)u2, true);
    float c0 = alpha[0];
    float c1 = alpha[1] * inv * IYSCALE;
    float c2 = alpha[2] * inv * IYSCALE;
    float c3 = alpha[3] * d   * IYSCALE;
    float4 v;
    v.x = c0 * e4.x + c1 * y1lo.x + c2 * y2lo.x + c3 * A.x;
    v.y = c0 * e4.y + c1 * y1lo.y + c2 * y2lo.y + c3 * A.y;
    v.z = c0 * e4.z + c1 * y1hi.x + c2 * y2hi.x + c3 * A.z;
    v.w = c0 * e4.w + c1 * y1hi.y + c2 * y2hi.y + c3 * A.w;
    if (n >= NUSERS) {
        float ss = v.x * v.x + v.y * v.y + v.z * v.z + v.w * v.w;
        #pragma unroll
        for (int m = 1; m < 16; m <<= 1) ss += __shfl_xor(ss, m);
        float nrm = fmaxf(sqrtf(ss), 1e-12f);
        float sc  = sf[0] / nrm;
        v.x *= sc; v.y *= sc; v.z *= sc; v.w *= sc;
    }
    if (lane < 16) ((float4*)acc)[o] = v;
}

// ---- rank[k] = dot(acc[src[k]], acc[dst[k]]) : 32 lanes per pair, float2 ----
__global__ void k_rank(const float* __restrict__ acc, const int* __restrict__ eli,
                       float* __restrict__ rank) {
    int k    = (blockIdx.x << 3) + (threadIdx.x >> 5);
    int q    = threadIdx.x & 31;
    if (k >= LABELS) return;
    int s = eli[k];
    int d = eli[LABELS + k];
    float2 vs = ((const float2*)acc)[(s << 5) + q];
    float2 vd = ((const float2*)acc)[(d << 5) + q];
    float p = vs.x * vd.x + vs.y * vd.y;
    #pragma unroll
    for (int m = 1; m < 32; m <<= 1) p += __shfl_xor(p, m);
    if (q == 0) rank[k] = p;
}

// ---- out[which][i][j] = rank[which*4096+j] + beta[eli[LABELS+which*4096+i]] ----
__global__ void k_final(const float* __restrict__ rank, const float* __restrict__ beta,
                        const int* __restrict__ eli, float* __restrict__ out) {
    int t     = blockIdx.x * blockDim.x + threadIdx.x;   // [0, 2^23)
    int which = t >> 22;
    int tt    = t & ((1 << 22) - 1);
    int i     = tt >> 10;
    int j4    = (tt & 1023) << 2;
    int item  = eli[LABELS + (which << 12) + i];
    float b   = beta[item];
    const float* rk = rank + (which << 12);
    float4 r = *reinterpret_cast<const float4*>(rk + j4);
    f32x4 vv = { r.x + b, r.y + b, r.z + b, r.w + b };
    __builtin_nontemporal_store(vv, reinterpret_cast<f32x4*>(out + ((size_t)t << 2)));
}

extern "C" void kernel_launch(void* const* d_in, const int* in_sizes, int n_in,
                              void* d_out, int out_size, void* d_ws, size_t ws_size,
                              hipStream_t stream) {
    const float* emb   = (const float*)d_in[0];
    const float* beta  = (const float*)d_in[1];
    const float* alpha = (const float*)d_in[2];
    const int*   eidx  = (const int*)d_in[3];
    const int*   eli   = (const int*)d_in[4];
    const float* sf    = (const float*)d_in[7];

    const int* row = eidx;
    const int* col = eidx + EDGES;

    // ---- workspace layout (4-byte units) ----
    char* ws = (char*)d_ws;
    int*   jpack = (int*)  (ws);                   // NODES
    float* dis   = (float*)(ws + 151552u * 4);     // NODES
    int*   gcur  = (int*)  (ws + 303104u * 4);     // NB2 (pad 1024)
    float* rank  = (float*)(ws + 304128u * 4);     // LABELS

    // d_out tail layout (dword units): acc, fp8 y ×3, E, src_s
    float*    acc   = (float*)d_out;                 // 9.6M f32
    unsigned* od    = (unsigned*)d_out;
    unsigned* Y0_8  = od + 10485760u;                // 2.4M dwords each
    unsigned* Y1_8  = od + 13107200u;
    unsigned* Y2_8  = od + 15728640u;
    unsigned* E     = od + 18350080u;                // NB2*BCAP = 4800512 dwords
    int*      src_s = (int*)(od + 23592960u);        // 4800512 dwords, ends < 28.4M

    const int NN4 = (NODES + 3) / 4;

    // ---- CSR build (fixed-capacity buckets; no chist/scan pass) ----
    k_init<<<2, 256, 0, stream>>>(gcur);
    k_cscatter<<<(EDGES + 8191) / 8192, 1024, 0, stream>>>(row, col, gcur, E);
    k_fsort<<<NB2, 512, 0, stream>>>(E, gcur, emb, src_s, jpack, dis, Y0_8);

    // ---- propagation (fp8 y-space, f32 accumulate) ----
    k_gather<<<NN4, 256, 0, stream>>>(Y0_8, src_s, jpack, dis, Y1_8);
    k_gather<<<NN4, 256, 0, stream>>>(Y1_8, src_s, jpack, dis, Y2_8);
    k_gather3<<<NN4, 256, 0, stream>>>(Y2_8, Y1_8, emb, src_s, jpack, dis,
                                       alpha, sf, acc);

    // ---- epilogue ----
    k_rank<<<LABELS / 8, 256, 0, stream>>>(acc, eli, rank);
    k_final<<<(1 << 23) / 256, 256, 0, stream>>>(rank, beta, eli, (float*)d_out);
}